// Round 1
// baseline (1038.648 us; speedup 1.0000x reference)
//
#include <hip/hip_runtime.h>

#define CCH 96      // channels
#define C4  24      // float4 groups per row
#define KK  27      // neighbors
#define NPB 128     // nodes per conv block
#define TPB 192     // threads per conv block: 8 groups x 24 lanes
#define GROUPS 8
#define NPT (NPB/GROUPS)   // nodes per thread = 16
#define BN_EPS 1e-5f

// ---------------- conv + per-block BN partial stats ----------------
__global__ __launch_bounds__(TPB) void octconv_kernel(
    const float* __restrict__ data,
    const int*   __restrict__ neigh32,   // may actually be int64; sniffed below
    const float* __restrict__ weight,
    float*       __restrict__ out,
    float*       __restrict__ partial,   // [gridDim.x][192]: 96 sum | 96 sumsq
    int N)
{
    __shared__ float w_lds[KK*CCH];      // 10368 B
    __shared__ int   nb_lds[NPB*KK];     // 13824 B
    __shared__ float red[2*GROUPS*CCH];  // 6144 B
    __shared__ int   flag_is64;

    const int tid = threadIdx.x;
    const int c4  = tid % C4;
    const int g   = tid / C4;
    const int base = blockIdx.x * NPB;
    const long long totalK = (long long)N * KK;

    // --- dtype sniff: int64 neigh (values < 2^31) has all-zero high words ---
    if (tid < 64) {
        int hi = neigh32[2*tid + 1];
        unsigned long long b = __ballot(hi != 0);
        if (tid == 0) flag_is64 = (b == 0ull) ? 1 : 0;
    }
    // --- stage weights ---
    for (int i = tid; i < KK*CCH; i += TPB) w_lds[i] = weight[i];
    __syncthreads();

    const bool is64 = (flag_is64 != 0);
    const long long* neigh64 = (const long long*)neigh32;

    // --- stage neighbor indices for this block's nodes ---
    for (int i = tid; i < NPB*KK; i += TPB) {
        long long gi = (long long)base * KK + i;
        int v = -1;
        if (gi < totalK) {
            if (is64) { long long vv = neigh64[gi]; v = (vv < 0) ? -1 : (int)vv; }
            else      { v = neigh32[gi]; }
        }
        nb_lds[i] = v;
    }
    __syncthreads();

    const float4* w4 = (const float4*)w_lds;
    float4 s = make_float4(0.f,0.f,0.f,0.f);
    float4 q = make_float4(0.f,0.f,0.f,0.f);

    for (int i = 0; i < NPT; ++i) {
        const int local = g * NPT + i;
        const int n = base + local;
        if (n < N) {
            float4 acc = make_float4(0.f,0.f,0.f,0.f);
            #pragma unroll
            for (int k = 0; k < KK; ++k) {
                const int idx = nb_lds[local*KK + k];
                if (idx >= 0) {
                    const float4 d = *(const float4*)(data + idx*CCH + c4*4);
                    const float4 w = w4[k*C4 + c4];
                    acc.x += d.x*w.x; acc.y += d.y*w.y;
                    acc.z += d.z*w.z; acc.w += d.w*w.w;
                }
            }
            *(float4*)(out + n*CCH + c4*4) = acc;
            s.x += acc.x; s.y += acc.y; s.z += acc.z; s.w += acc.w;
            q.x += acc.x*acc.x; q.y += acc.y*acc.y;
            q.z += acc.z*acc.z; q.w += acc.w*acc.w;
        }
    }

    // --- per-block channel reduction across the 8 groups ---
    *(float4*)(&red[(0*GROUPS + g)*CCH + c4*4]) = s;
    *(float4*)(&red[(1*GROUPS + g)*CCH + c4*4]) = q;
    __syncthreads();
    if (g == 0) {
        float4 ts = make_float4(0.f,0.f,0.f,0.f);
        float4 tq = make_float4(0.f,0.f,0.f,0.f);
        #pragma unroll
        for (int gg = 0; gg < GROUPS; ++gg) {
            float4 a = *(float4*)(&red[(0*GROUPS+gg)*CCH + c4*4]);
            float4 b = *(float4*)(&red[(1*GROUPS+gg)*CCH + c4*4]);
            ts.x+=a.x; ts.y+=a.y; ts.z+=a.z; ts.w+=a.w;
            tq.x+=b.x; tq.y+=b.y; tq.z+=b.z; tq.w+=b.w;
        }
        *(float4*)(partial + blockIdx.x*2*CCH + c4*4)        = ts;
        *(float4*)(partial + blockIdx.x*2*CCH + CCH + c4*4)  = tq;
    }
}

// ---------------- stage-1 reduce of per-block partials ----------------
__global__ __launch_bounds__(192) void reduce1_kernel(
    const float* __restrict__ partial, float* __restrict__ out2, int nblocks)
{
    const int col = threadIdx.x;   // 0..191
    float s = 0.f;
    for (int r = blockIdx.x; r < nblocks; r += gridDim.x)
        s += partial[r*192 + col];
    out2[blockIdx.x*192 + col] = s;
}

// ---------------- stage-2 reduce + compute scale/shift ----------------
__global__ __launch_bounds__(192) void reduce2_kernel(
    const float* __restrict__ in2,      // [96][192]
    const float* __restrict__ gamma,
    const float* __restrict__ beta,
    float* __restrict__ scaleshift,     // [192]: 96 scale | 96 shift
    int N)
{
    __shared__ float arr[192];
    const int col = threadIdx.x;
    float s = 0.f;
    for (int r = 0; r < 96; ++r) s += in2[r*192 + col];
    arr[col] = s;
    __syncthreads();
    if (col < CCH) {
        float invN = 1.f / (float)N;
        float mean = arr[col] * invN;
        float var  = arr[CCH + col] * invN - mean*mean;
        float sc   = gamma[col] * rsqrtf(var + BN_EPS);
        scaleshift[col]       = sc;
        scaleshift[CCH + col] = beta[col] - mean*sc;
    }
}

// ---------------- apply BN in place ----------------
__global__ __launch_bounds__(256) void bn_apply_kernel(
    float* __restrict__ out, const float* __restrict__ scaleshift, long long total4)
{
    __shared__ float4 sc[C4], sh[C4];
    const int tid = threadIdx.x;
    if (tid < C4) {
        sc[tid] = ((const float4*)scaleshift)[tid];
        sh[tid] = ((const float4*)(scaleshift + CCH))[tid];
    }
    __syncthreads();
    // grid*block chosen divisible by 24 -> c4 constant per thread
    const long long stride = (long long)gridDim.x * blockDim.x;
    long long i = (long long)blockIdx.x * blockDim.x + tid;
    const int c4 = (int)(i % C4);
    const float4 a = sc[c4], b = sh[c4];
    float4* o4 = (float4*)out;
    for (; i < total4; i += stride) {
        float4 v = o4[i];
        v.x = v.x*a.x + b.x; v.y = v.y*a.y + b.y;
        v.z = v.z*a.z + b.z; v.w = v.w*a.w + b.w;
        o4[i] = v;
    }
}

extern "C" void kernel_launch(void* const* d_in, const int* in_sizes, int n_in,
                              void* d_out, int out_size, void* d_ws, size_t ws_size,
                              hipStream_t stream) {
    const float* data   = (const float*)d_in[0];
    const int*   neigh  = (const int*)d_in[1];
    const float* weight = (const float*)d_in[2];
    const float* gamma  = (const float*)d_in[3];
    const float* beta   = (const float*)d_in[4];
    float* out = (float*)d_out;

    const int N = in_sizes[0] / CCH;
    const int nblocks = (N + NPB - 1) / NPB;

    float* wsA = (float*)d_ws;                       // [nblocks][192]
    float* wsB = wsA + (size_t)nblocks * 192;        // [96][192]
    float* wsC = wsB + 96 * 192;                     // [192]

    octconv_kernel<<<nblocks, TPB, 0, stream>>>(data, neigh, weight, out, wsA, N);
    reduce1_kernel<<<96, 192, 0, stream>>>(wsA, wsB, nblocks);
    reduce2_kernel<<<1, 192, 0, stream>>>(wsB, gamma, beta, wsC, N);
    // 2040*256 = 522240 threads, divisible by 24
    bn_apply_kernel<<<2040, 256, 0, stream>>>(out, wsC, (long long)N * C4);
}

// Round 3
// 1026.671 us; speedup vs baseline: 1.0117x; 1.0117x over previous
//
#include <hip/hip_runtime.h>

#define CCH 96      // channels
#define C4  24      // float4 groups per row
#define KK  27      // neighbors
#define NPB 64      // nodes per conv block
#define TPB 192     // threads per conv block: 8 groups x 24 lanes
#define GROUPS 8
#define NPT (NPB/GROUPS)   // nodes per thread = 8
#define BN_EPS 1e-5f

typedef float floatx4 __attribute__((ext_vector_type(4)));

// ---------------- conv + per-block BN partial stats ----------------
// LDS: w_lds 10368 B + union(nb 6912 B, red 3072 B) = ~17.3 KB -> 9 blocks/CU
__global__ __launch_bounds__(TPB) void octconv_kernel(
    const float* __restrict__ data,
    const int*   __restrict__ neigh32,   // may actually be int64; sniffed below
    const float* __restrict__ weight,
    float*       __restrict__ out,
    float*       __restrict__ partial,   // [gridDim.x][192]: 96 sum | 96 sumsq
    int N)
{
    __shared__ float w_lds[KK*CCH];                  // 10368 B
    __shared__ __align__(16) char u_lds[NPB*KK*4];   // 6912 B (nb, then red)
    __shared__ int   flag_is64;
    int*   nb_lds = (int*)u_lds;
    float* red    = (float*)u_lds;                   // [GROUPS][CCH] after compute

    const int tid = threadIdx.x;
    const int c4  = tid % C4;
    const int g   = tid / C4;
    const int base = blockIdx.x * NPB;
    const long long totalK = (long long)N * KK;

    // --- dtype sniff: int64 neigh (values < 2^31) has all-zero high words ---
    if (tid < 64) {
        int hi = neigh32[2*tid + 1];
        unsigned long long b = __ballot(hi != 0);
        if (tid == 0) flag_is64 = (b == 0ull) ? 1 : 0;
    }
    // --- stage weights ---
    for (int i = tid; i < KK*CCH; i += TPB) w_lds[i] = weight[i];
    __syncthreads();

    const bool is64 = (flag_is64 != 0);
    const long long* neigh64 = (const long long*)neigh32;

    // --- stage neighbor indices for this block's nodes (streamed once: NT) ---
    for (int i = tid; i < NPB*KK; i += TPB) {
        long long gi = (long long)base * KK + i;
        int v = -1;
        if (gi < totalK) {
            if (is64) {
                long long vv = __builtin_nontemporal_load(neigh64 + gi);
                v = (vv < 0) ? -1 : (int)vv;
            } else {
                v = __builtin_nontemporal_load(neigh32 + gi);
            }
        }
        nb_lds[i] = v;
    }
    __syncthreads();

    const float4* w4 = (const float4*)w_lds;
    float4 s = make_float4(0.f,0.f,0.f,0.f);
    float4 q = make_float4(0.f,0.f,0.f,0.f);

    for (int i = 0; i < NPT; ++i) {
        const int local = g * NPT + i;
        const int n = base + local;
        if (n < N) {
            float4 acc = make_float4(0.f,0.f,0.f,0.f);
            #pragma unroll
            for (int k = 0; k < KK; ++k) {
                const int idx = nb_lds[local*KK + k];
                if (idx >= 0) {
                    const float4 d = *(const float4*)(data + idx*CCH + c4*4);
                    const float4 w = w4[k*C4 + c4];
                    acc.x += d.x*w.x; acc.y += d.y*w.y;
                    acc.z += d.z*w.z; acc.w += d.w*w.w;
                }
            }
            // streaming store: don't evict gather-reused `data` from L2
            floatx4 av; av.x = acc.x; av.y = acc.y; av.z = acc.z; av.w = acc.w;
            __builtin_nontemporal_store(av, (floatx4*)(out + n*CCH + c4*4));
            s.x += acc.x; s.y += acc.y; s.z += acc.z; s.w += acc.w;
            q.x += acc.x*acc.x; q.y += acc.y*acc.y;
            q.z += acc.z*acc.z; q.w += acc.w*acc.w;
        }
    }

    // --- per-block channel reduction across the 8 groups (reuses nb_lds) ---
    __syncthreads();                                  // done reading nb_lds
    *(float4*)(&red[g*CCH + c4*4]) = s;
    __syncthreads();
    if (g == 0) {
        float4 ts = make_float4(0.f,0.f,0.f,0.f);
        #pragma unroll
        for (int gg = 0; gg < GROUPS; ++gg) {
            float4 a = *(float4*)(&red[gg*CCH + c4*4]);
            ts.x+=a.x; ts.y+=a.y; ts.z+=a.z; ts.w+=a.w;
        }
        *(float4*)(partial + blockIdx.x*2*CCH + c4*4) = ts;
    }
    __syncthreads();
    *(float4*)(&red[g*CCH + c4*4]) = q;
    __syncthreads();
    if (g == 0) {
        float4 tq = make_float4(0.f,0.f,0.f,0.f);
        #pragma unroll
        for (int gg = 0; gg < GROUPS; ++gg) {
            float4 b = *(float4*)(&red[gg*CCH + c4*4]);
            tq.x+=b.x; tq.y+=b.y; tq.z+=b.z; tq.w+=b.w;
        }
        *(float4*)(partial + blockIdx.x*2*CCH + CCH + c4*4) = tq;
    }
}

// ---------------- stage-1 reduce of per-block partials ----------------
__global__ __launch_bounds__(192) void reduce1_kernel(
    const float* __restrict__ partial, float* __restrict__ out2, int nblocks)
{
    const int col = threadIdx.x;   // 0..191
    float s = 0.f;
    for (int r = blockIdx.x; r < nblocks; r += gridDim.x)
        s += partial[r*192 + col];
    out2[blockIdx.x*192 + col] = s;
}

// ---------------- stage-2 reduce + compute scale/shift ----------------
__global__ __launch_bounds__(192) void reduce2_kernel(
    const float* __restrict__ in2,      // [96][192]
    const float* __restrict__ gamma,
    const float* __restrict__ beta,
    float* __restrict__ scaleshift,     // [192]: 96 scale | 96 shift
    int N)
{
    __shared__ float arr[192];
    const int col = threadIdx.x;
    float s = 0.f;
    for (int r = 0; r < 96; ++r) s += in2[r*192 + col];
    arr[col] = s;
    __syncthreads();
    if (col < CCH) {
        float invN = 1.f / (float)N;
        float mean = arr[col] * invN;
        float var  = arr[CCH + col] * invN - mean*mean;
        float sc   = gamma[col] * rsqrtf(var + BN_EPS);
        scaleshift[col]       = sc;
        scaleshift[CCH + col] = beta[col] - mean*sc;
    }
}

// ---------------- apply BN in place ----------------
__global__ __launch_bounds__(256) void bn_apply_kernel(
    float* __restrict__ out, const float* __restrict__ scaleshift, long long total4)
{
    __shared__ float4 sc[C4], sh[C4];
    const int tid = threadIdx.x;
    if (tid < C4) {
        sc[tid] = ((const float4*)scaleshift)[tid];
        sh[tid] = ((const float4*)(scaleshift + CCH))[tid];
    }
    __syncthreads();
    // grid*block chosen divisible by 24 -> c4 constant per thread
    const long long stride = (long long)gridDim.x * blockDim.x;
    long long i = (long long)blockIdx.x * blockDim.x + tid;
    const int c4 = (int)(i % C4);
    const float4 a = sc[c4], b = sh[c4];
    float4* o4 = (float4*)out;
    for (; i < total4; i += stride) {
        float4 v = o4[i];
        v.x = v.x*a.x + b.x; v.y = v.y*a.y + b.y;
        v.z = v.z*a.z + b.z; v.w = v.w*a.w + b.w;
        o4[i] = v;
    }
}

extern "C" void kernel_launch(void* const* d_in, const int* in_sizes, int n_in,
                              void* d_out, int out_size, void* d_ws, size_t ws_size,
                              hipStream_t stream) {
    const float* data   = (const float*)d_in[0];
    const int*   neigh  = (const int*)d_in[1];
    const float* weight = (const float*)d_in[2];
    const float* gamma  = (const float*)d_in[3];
    const float* beta   = (const float*)d_in[4];
    float* out = (float*)d_out;

    const int N = in_sizes[0] / CCH;
    const int nblocks = (N + NPB - 1) / NPB;

    float* wsA = (float*)d_ws;                       // [nblocks][192]
    float* wsB = wsA + (size_t)nblocks * 192;        // [96][192]
    float* wsC = wsB + 96 * 192;                     // [192]

    octconv_kernel<<<nblocks, TPB, 0, stream>>>(data, neigh, weight, out, wsA, N);
    reduce1_kernel<<<96, 192, 0, stream>>>(wsA, wsB, nblocks);
    reduce2_kernel<<<1, 192, 0, stream>>>(wsB, gamma, beta, wsC, N);
    // 2040*256 = 522240 threads, divisible by 24
    bn_apply_kernel<<<2040, 256, 0, stream>>>(out, wsC, (long long)N * C4);
}